// Round 1
// baseline (5580.309 us; speedup 1.0000x reference)
//
#include <hip/hip_runtime.h>
#include <cstddef>

#define NN 100000
#define EE 1600000
#define FF 128

// ---------------- copy (s = x) ----------------
__global__ __launch_bounds__(256) void copy4(const float4* __restrict__ s,
                                             float4* __restrict__ d, int n) {
  int i = blockIdx.x * 256 + threadIdx.x;
  if (i < n) d[i] = s[i];
}

// ---------------- scatter: acc[dst] += feat[src] ----------------
// 32 lanes per edge, float4 per lane (128 floats / edge).
__global__ __launch_bounds__(256) void scatter_add(const float* __restrict__ feat,
                                                   float* __restrict__ acc,
                                                   const int* __restrict__ ei) {
  int tid = blockIdx.x * 256 + threadIdx.x;
  int e = tid >> 5;
  if (e >= EE) return;
  int l = tid & 31;
  int src = ei[e];
  int dst = ei[EE + e];
  float4 v = ((const float4*)(feat + (size_t)src * FF))[l];
  float* a = acc + (size_t)dst * FF + (size_t)l * 4;
  atomicAdd(a + 0, v.x);
  atomicAdd(a + 1, v.y);
  atomicAdd(a + 2, v.z);
  atomicAdd(a + 3, v.w);
}

// ---------------- fp32 GEMM: out = in(nrows x 128) @ w(128x128) + epilogue --------
// Block: 256 thr, tile 128 rows x 128 cols, per-thread 8x8.
// LDS: in^T chunk [16][128] + w chunk [16][128] (16 KB total).
template <bool BN>
__global__ __launch_bounds__(256) void gemm128(const float* __restrict__ in,
    const float* __restrict__ w, const float* __restrict__ bias,
    const float* __restrict__ gamma, const float* __restrict__ beta,
    const float* __restrict__ rmean, const float* __restrict__ rvar,
    float* __restrict__ out0, float* __restrict__ out1, int nrows)
{
  __shared__ float in_sT[16][FF];
  __shared__ float w_s[16][FF];
  const int tid = threadIdx.x;
  const int tj = tid & 15;   // col group: cols 8*tj..8*tj+7
  const int tr = tid >> 4;   // row group: rows 8*tr..8*tr+7
  const int row0 = blockIdx.x * 128;
  float acc[8][8] = {};

  const int lr = tid & 127;      // loader: row within tile
  const int lq = tid >> 7;       // loader: 0/1
  const int wr = tid >> 5;       // w loader row 0..7
  const int wc = (tid & 31) * 4; // w loader col
  const int grow = min(row0 + lr, nrows - 1); // clamp tail rows (results discarded)
  const float* inrow = in + (size_t)grow * FF;

  for (int kc = 0; kc < FF; kc += 16) {
    float4 a0 = *(const float4*)(inrow + kc + 4 * lq);
    float4 a1 = *(const float4*)(inrow + kc + 8 + 4 * lq);
    float4 wv0 = *(const float4*)(w + (size_t)(kc + wr) * FF + wc);
    float4 wv1 = *(const float4*)(w + (size_t)(kc + wr + 8) * FF + wc);
    __syncthreads();
    in_sT[4*lq+0][lr] = a0.x;  in_sT[4*lq+1][lr] = a0.y;
    in_sT[4*lq+2][lr] = a0.z;  in_sT[4*lq+3][lr] = a0.w;
    in_sT[4*lq+8][lr] = a1.x;  in_sT[4*lq+9][lr] = a1.y;
    in_sT[4*lq+10][lr] = a1.z; in_sT[4*lq+11][lr] = a1.w;
    *(float4*)&w_s[wr][wc] = wv0;
    *(float4*)&w_s[wr + 8][wc] = wv1;
    __syncthreads();
#pragma unroll
    for (int k = 0; k < 16; ++k) {
      float4 av0 = *(const float4*)&in_sT[k][8 * tr];
      float4 av1 = *(const float4*)&in_sT[k][8 * tr + 4];
      float4 bv0 = *(const float4*)&w_s[k][8 * tj];
      float4 bv1 = *(const float4*)&w_s[k][8 * tj + 4];
      float a[8] = {av0.x, av0.y, av0.z, av0.w, av1.x, av1.y, av1.z, av1.w};
      float b[8] = {bv0.x, bv0.y, bv0.z, bv0.w, bv1.x, bv1.y, bv1.z, bv1.w};
#pragma unroll
      for (int i = 0; i < 8; ++i)
#pragma unroll
        for (int j = 0; j < 8; ++j)
          acc[i][j] = fmaf(a[i], b[j], acc[i][j]);
    }
  }

  // epilogue: fold bias (+ BN) into per-col scale/shift
  const int c0 = 8 * tj;
  float sc[8], sh[8];
#pragma unroll
  for (int j = 0; j < 8; ++j) {
    if (BN) {
      float s = gamma[c0 + j] * rsqrtf(rvar[c0 + j] + 1e-5f);
      sc[j] = s;
      sh[j] = (bias[c0 + j] - rmean[c0 + j]) * s + beta[c0 + j];
    } else {
      sc[j] = 1.0f;
      sh[j] = bias[c0 + j];
    }
  }
#pragma unroll
  for (int i = 0; i < 8; ++i) {
    int r = row0 + 8 * tr + i;
    if (r < nrows) {
      float o[8];
#pragma unroll
      for (int j = 0; j < 8; ++j) {
        float v = fmaf(acc[i][j], sc[j], sh[j]);
        if (BN) v = fmaxf(v, 0.0f);
        o[j] = v;
      }
      float4* p0 = (float4*)(out0 + (size_t)r * FF + c0);
      p0[0] = make_float4(o[0], o[1], o[2], o[3]);
      p0[1] = make_float4(o[4], o[5], o[6], o[7]);
      if (out1) {
        float4* p1 = (float4*)(out1 + (size_t)r * FF + c0);
        p1[0] = make_float4(o[0], o[1], o[2], o[3]);
        p1[1] = make_float4(o[4], o[5], o[6], o[7]);
      }
    }
  }
}

extern "C" void kernel_launch(void* const* d_in, const int* in_sizes, int n_in,
                              void* d_out, int out_size, void* d_ws, size_t ws_size,
                              hipStream_t stream) {
  const float* x     = (const float*)d_in[0];
  const int*   ei    = (const int*)d_in[1];
  const float* w0    = (const float*)d_in[2];
  const float* b0    = (const float*)d_in[3];
  const float* gamma = (const float*)d_in[4];
  const float* beta  = (const float*)d_in[5];
  const float* rmean = (const float*)d_in[6];
  const float* rvar  = (const float*)d_in[7];
  const float* w1    = (const float*)d_in[8];
  const float* b1    = (const float*)d_in[9];
  float* out = (float*)d_out;

  float* s = (float*)d_ws;                       // 100000*128 floats
  float* h = s + (size_t)NN * FF;                // 100000*128 floats

  const int n4 = NN * FF / 4;                    // 3,200,000 float4
  const int scatter_blocks = EE / 8;             // 8 edges per 256-thr block
  const int gemm_blocks = (NN + 127) / 128;      // 782

  // s = x
  copy4<<<(n4 + 255) / 256, 256, 0, stream>>>((const float4*)x, (float4*)s, n4);
  // s[dst] += x[src]
  scatter_add<<<scatter_blocks, 256, 0, stream>>>(x, s, ei);
  // h = relu(BN(s@w0 + b0)); also s := h (in-place re-init for layer 2)
  gemm128<true><<<gemm_blocks, 256, 0, stream>>>(s, w0, b0, gamma, beta, rmean, rvar,
                                                 h, s, NN);
  // s[dst] += h[src]
  scatter_add<<<scatter_blocks, 256, 0, stream>>>(h, s, ei);
  // out = s@w1 + b1
  gemm128<false><<<gemm_blocks, 256, 0, stream>>>(s, w1, b1, nullptr, nullptr, nullptr,
                                                  nullptr, out, nullptr, NN);
}

// Round 3
// 638.308 us; speedup vs baseline: 8.7423x; 8.7423x over previous
//
#include <hip/hip_runtime.h>
#include <cstddef>

#define NN 100000
#define EE 1600000
#define FF 128
#define NCHUNK ((NN + 255) / 256)   // 391

// ---------------- CSR build ----------------
__global__ __launch_bounds__(256) void hist(const int* __restrict__ ei,
                                            int* __restrict__ counts) {
  int e = blockIdx.x * 256 + threadIdx.x;
  if (e < EE) atomicAdd(&counts[ei[EE + e]], 1);
}

// per-chunk (256-elem) inclusive scan; chunk b == block b
__global__ __launch_bounds__(256) void scan_chunks(const int* __restrict__ counts,
                                                   int* __restrict__ incl,
                                                   int* __restrict__ chunkSum) {
  __shared__ int sd[256];
  int i = blockIdx.x * 256 + threadIdx.x;
  sd[threadIdx.x] = (i < NN) ? counts[i] : 0;
  __syncthreads();
  for (int off = 1; off < 256; off <<= 1) {
    int t = 0;
    if ((int)threadIdx.x >= off) t = sd[threadIdx.x - off];
    __syncthreads();
    if ((int)threadIdx.x >= off) sd[threadIdx.x] += t;
    __syncthreads();
  }
  if (i < NN) incl[i] = sd[threadIdx.x];
  if (threadIdx.x == 255) chunkSum[blockIdx.x] = sd[255];
}

// single block: inclusive scan of the 391 chunk sums (padded to 512)
__global__ __launch_bounds__(512) void scan_sums(int* __restrict__ chunkSum) {
  __shared__ int sd[512];
  sd[threadIdx.x] = (threadIdx.x < NCHUNK) ? chunkSum[threadIdx.x] : 0;
  __syncthreads();
  for (int off = 1; off < 512; off <<= 1) {
    int t = 0;
    if ((int)threadIdx.x >= off) t = sd[threadIdx.x - off];
    __syncthreads();
    if ((int)threadIdx.x >= off) sd[threadIdx.x] += t;
    __syncthreads();
  }
  if (threadIdx.x < NCHUNK) chunkSum[threadIdx.x] = sd[threadIdx.x];
}

__global__ __launch_bounds__(256) void finalize(const int* __restrict__ counts,
                                                const int* __restrict__ incl,
                                                const int* __restrict__ chunkSum,
                                                int* __restrict__ offsets,
                                                int* __restrict__ cursor) {
  int i = blockIdx.x * 256 + threadIdx.x;
  if (i < NN) {
    int base = (blockIdx.x > 0) ? chunkSum[blockIdx.x - 1] : 0;
    int off = base + incl[i] - counts[i];   // exclusive prefix
    offsets[i] = off;
    cursor[i] = off;
  }
  if (i == 0) offsets[NN] = EE;
}

__global__ __launch_bounds__(256) void fill(const int* __restrict__ ei,
                                            int* __restrict__ cursor,
                                            int* __restrict__ csr) {
  int e = blockIdx.x * 256 + threadIdx.x;
  if (e < EE) {
    int p = atomicAdd(&cursor[ei[EE + e]], 1);
    csr[p] = ei[e];
  }
}

// ---------------- gather-reduce: out[n] = feat[n] + sum_{j in N(n)} feat[j] ----
// 32 lanes per node, float4 per lane; neighbor rows are L3-resident.
__global__ __launch_bounds__(256) void gather(const float* __restrict__ feat,
                                              const int* __restrict__ offsets,
                                              const int* __restrict__ csr,
                                              float* __restrict__ out) {
  int g = (blockIdx.x * 256 + threadIdx.x) >> 5;
  int l = threadIdx.x & 31;
  if (g >= NN) return;
  int beg = offsets[g];
  int end = offsets[g + 1];
  float4 acc = ((const float4*)(feat + (size_t)g * FF))[l];
  int j = beg;
  for (; j + 4 <= end; j += 4) {
    int i0 = csr[j], i1 = csr[j + 1], i2 = csr[j + 2], i3 = csr[j + 3];
    float4 v0 = ((const float4*)(feat + (size_t)i0 * FF))[l];
    float4 v1 = ((const float4*)(feat + (size_t)i1 * FF))[l];
    float4 v2 = ((const float4*)(feat + (size_t)i2 * FF))[l];
    float4 v3 = ((const float4*)(feat + (size_t)i3 * FF))[l];
    acc.x += (v0.x + v1.x) + (v2.x + v3.x);
    acc.y += (v0.y + v1.y) + (v2.y + v3.y);
    acc.z += (v0.z + v1.z) + (v2.z + v3.z);
    acc.w += (v0.w + v1.w) + (v2.w + v3.w);
  }
  for (; j < end; ++j) {
    int i0 = csr[j];
    float4 v = ((const float4*)(feat + (size_t)i0 * FF))[l];
    acc.x += v.x; acc.y += v.y; acc.z += v.z; acc.w += v.w;
  }
  ((float4*)(out + (size_t)g * FF))[l] = acc;
}

// ---------------- fp32 GEMM: out = in(nrows x 128) @ w(128x128) + epilogue --------
template <bool BN>
__global__ __launch_bounds__(256) void gemm128(const float* __restrict__ in,
    const float* __restrict__ w, const float* __restrict__ bias,
    const float* __restrict__ gamma, const float* __restrict__ beta,
    const float* __restrict__ rmean, const float* __restrict__ rvar,
    float* __restrict__ out0, int nrows)
{
  __shared__ float in_sT[16][FF];
  __shared__ float w_s[16][FF];
  const int tid = threadIdx.x;
  const int tj = tid & 15;   // col group: cols 8*tj..8*tj+7
  const int tr = tid >> 4;   // row group: rows 8*tr..8*tr+7
  const int row0 = blockIdx.x * 128;
  float acc[8][8] = {};

  const int lr = tid & 127;      // loader: row within tile
  const int lq = tid >> 7;       // loader: 0/1
  const int wr = tid >> 5;       // w loader row 0..7
  const int wc = (tid & 31) * 4; // w loader col
  const int grow = min(row0 + lr, nrows - 1); // clamp tail rows (discarded)
  const float* inrow = in + (size_t)grow * FF;

  for (int kc = 0; kc < FF; kc += 16) {
    float4 a0 = *(const float4*)(inrow + kc + 4 * lq);
    float4 a1 = *(const float4*)(inrow + kc + 8 + 4 * lq);
    float4 wv0 = *(const float4*)(w + (size_t)(kc + wr) * FF + wc);
    float4 wv1 = *(const float4*)(w + (size_t)(kc + wr + 8) * FF + wc);
    __syncthreads();
    in_sT[4*lq+0][lr] = a0.x;  in_sT[4*lq+1][lr] = a0.y;
    in_sT[4*lq+2][lr] = a0.z;  in_sT[4*lq+3][lr] = a0.w;
    in_sT[4*lq+8][lr] = a1.x;  in_sT[4*lq+9][lr] = a1.y;
    in_sT[4*lq+10][lr] = a1.z; in_sT[4*lq+11][lr] = a1.w;
    *(float4*)&w_s[wr][wc] = wv0;
    *(float4*)&w_s[wr + 8][wc] = wv1;
    __syncthreads();
#pragma unroll
    for (int k = 0; k < 16; ++k) {
      float4 av0 = *(const float4*)&in_sT[k][8 * tr];
      float4 av1 = *(const float4*)&in_sT[k][8 * tr + 4];
      float4 bv0 = *(const float4*)&w_s[k][8 * tj];
      float4 bv1 = *(const float4*)&w_s[k][8 * tj + 4];
      float a[8] = {av0.x, av0.y, av0.z, av0.w, av1.x, av1.y, av1.z, av1.w};
      float b[8] = {bv0.x, bv0.y, bv0.z, bv0.w, bv1.x, bv1.y, bv1.z, bv1.w};
#pragma unroll
      for (int i = 0; i < 8; ++i)
#pragma unroll
        for (int j = 0; j < 8; ++j)
          acc[i][j] = fmaf(a[i], b[j], acc[i][j]);
    }
  }

  const int c0 = 8 * tj;
  float sc[8], sh[8];
#pragma unroll
  for (int j = 0; j < 8; ++j) {
    if (BN) {
      float s = gamma[c0 + j] * rsqrtf(rvar[c0 + j] + 1e-5f);
      sc[j] = s;
      sh[j] = (bias[c0 + j] - rmean[c0 + j]) * s + beta[c0 + j];
    } else {
      sc[j] = 1.0f;
      sh[j] = bias[c0 + j];
    }
  }
#pragma unroll
  for (int i = 0; i < 8; ++i) {
    int r = row0 + 8 * tr + i;
    if (r < nrows) {
      float o[8];
#pragma unroll
      for (int j = 0; j < 8; ++j) {
        float v = fmaf(acc[i][j], sc[j], sh[j]);
        if (BN) v = fmaxf(v, 0.0f);
        o[j] = v;
      }
      float4* p0 = (float4*)(out0 + (size_t)r * FF + c0);
      p0[0] = make_float4(o[0], o[1], o[2], o[3]);
      p0[1] = make_float4(o[4], o[5], o[6], o[7]);
    }
  }
}

extern "C" void kernel_launch(void* const* d_in, const int* in_sizes, int n_in,
                              void* d_out, int out_size, void* d_ws, size_t ws_size,
                              hipStream_t stream) {
  const float* x     = (const float*)d_in[0];
  const int*   ei    = (const int*)d_in[1];
  const float* w0    = (const float*)d_in[2];
  const float* b0    = (const float*)d_in[3];
  const float* gamma = (const float*)d_in[4];
  const float* beta  = (const float*)d_in[5];
  const float* rmean = (const float*)d_in[6];
  const float* rvar  = (const float*)d_in[7];
  const float* w1    = (const float*)d_in[8];
  const float* b1    = (const float*)d_in[9];
  float* out = (float*)d_out;

  // workspace layout
  float* s = (float*)d_ws;                       // NN*FF floats (51.2 MB)
  float* h = s + (size_t)NN * FF;                // NN*FF floats (51.2 MB)
  int* counts   = (int*)(h + (size_t)NN * FF);   // NN
  int* incl     = counts + NN;                   // NN
  int* chunkSum = incl + NN;                     // 512
  int* offsets  = chunkSum + 512;                // NN+1
  int* cursor   = offsets + NN + 1;              // NN
  int* csr      = cursor + NN;                   // EE

  const int eb = (EE + 255) / 256;               // 6250
  const int gatherb = (NN * 32 + 255) / 256;     // 12500
  const int gemmb = (NN + 127) / 128;            // 782

  // ---- CSR build (per call; edges are a runtime input) ----
  (void)hipMemsetAsync(counts, 0, (size_t)NN * sizeof(int), stream);
  hist<<<eb, 256, 0, stream>>>(ei, counts);
  scan_chunks<<<NCHUNK, 256, 0, stream>>>(counts, incl, chunkSum);
  scan_sums<<<1, 512, 0, stream>>>(chunkSum);
  finalize<<<NCHUNK, 256, 0, stream>>>(counts, incl, chunkSum, offsets, cursor);
  fill<<<eb, 256, 0, stream>>>(ei, cursor, csr);

  // ---- layer 1 ----
  gather<<<gatherb, 256, 0, stream>>>(x, offsets, csr, s);          // s = x + agg(x)
  gemm128<true><<<gemmb, 256, 0, stream>>>(s, w0, b0, gamma, beta, rmean, rvar,
                                           h, NN);                  // h = relu(BN(s@w0+b0))
  // ---- layer 2 ----
  gather<<<gatherb, 256, 0, stream>>>(h, offsets, csr, s);          // s = h + agg(h)
  gemm128<false><<<gemmb, 256, 0, stream>>>(s, w1, b1, nullptr, nullptr, nullptr, nullptr,
                                            out, NN);               // out = s@w1+b1
}

// Round 5
// 537.682 us; speedup vs baseline: 10.3784x; 1.1871x over previous
//
#include <hip/hip_runtime.h>
#include <cstddef>

#define NN 100000
#define EE 1600000
#define FF 128
#define NCHUNK ((NN + 255) / 256)   // 391

typedef unsigned int uint;
typedef unsigned short ushort;

__device__ __forceinline__ ushort f2bf(float f) {
  uint u = __float_as_uint(f);
  uint r = u + 0x7fffu + ((u >> 16) & 1u);   // RNE
  return (ushort)(r >> 16);
}
__device__ __forceinline__ uint pack2(float a, float b) {
  return (uint)f2bf(a) | ((uint)f2bf(b) << 16);
}
// accumulate 8 bf16 (one uint4) into 8 fp32
__device__ __forceinline__ void acc8(float* a, uint4 v) {
  a[0] += __uint_as_float(v.x << 16);
  a[1] += __uint_as_float(v.x & 0xffff0000u);
  a[2] += __uint_as_float(v.y << 16);
  a[3] += __uint_as_float(v.y & 0xffff0000u);
  a[4] += __uint_as_float(v.z << 16);
  a[5] += __uint_as_float(v.z & 0xffff0000u);
  a[6] += __uint_as_float(v.w << 16);
  a[7] += __uint_as_float(v.w & 0xffff0000u);
}

// ---------------- x -> bf16 (8 floats / thread) ----------------
__global__ __launch_bounds__(256) void cvt_bf16(const float4* __restrict__ x,
                                                uint4* __restrict__ xb, int n8) {
  int i = blockIdx.x * 256 + threadIdx.x;
  if (i >= n8) return;
  float4 a = x[2 * i];
  float4 b = x[2 * i + 1];
  uint4 o;
  o.x = pack2(a.x, a.y);
  o.y = pack2(a.z, a.w);
  o.z = pack2(b.x, b.y);
  o.w = pack2(b.z, b.w);
  xb[i] = o;
}

// ---------------- CSR build ----------------
__global__ __launch_bounds__(256) void hist(const int* __restrict__ ei,
                                            int* __restrict__ counts) {
  int e = blockIdx.x * 256 + threadIdx.x;
  if (e < EE) atomicAdd(&counts[ei[EE + e]], 1);
}

__global__ __launch_bounds__(256) void scan_chunks(const int* __restrict__ counts,
                                                   int* __restrict__ incl,
                                                   int* __restrict__ chunkSum) {
  __shared__ int sd[256];
  int i = blockIdx.x * 256 + threadIdx.x;
  sd[threadIdx.x] = (i < NN) ? counts[i] : 0;
  __syncthreads();
  for (int off = 1; off < 256; off <<= 1) {
    int t = 0;
    if ((int)threadIdx.x >= off) t = sd[threadIdx.x - off];
    __syncthreads();
    if ((int)threadIdx.x >= off) sd[threadIdx.x] += t;
    __syncthreads();
  }
  if (i < NN) incl[i] = sd[threadIdx.x];
  if (threadIdx.x == 255) chunkSum[blockIdx.x] = sd[255];
}

__global__ __launch_bounds__(512) void scan_sums(int* __restrict__ chunkSum) {
  __shared__ int sd[512];
  sd[threadIdx.x] = (threadIdx.x < NCHUNK) ? chunkSum[threadIdx.x] : 0;
  __syncthreads();
  for (int off = 1; off < 512; off <<= 1) {
    int t = 0;
    if ((int)threadIdx.x >= off) t = sd[threadIdx.x - off];
    __syncthreads();
    if ((int)threadIdx.x >= off) sd[threadIdx.x] += t;
    __syncthreads();
  }
  if (threadIdx.x < NCHUNK) chunkSum[threadIdx.x] = sd[threadIdx.x];
}

__global__ __launch_bounds__(256) void finalize(const int* __restrict__ counts,
                                                const int* __restrict__ incl,
                                                const int* __restrict__ chunkSum,
                                                int* __restrict__ offsets,
                                                int* __restrict__ cursor) {
  int i = blockIdx.x * 256 + threadIdx.x;
  if (i < NN) {
    int base = (blockIdx.x > 0) ? chunkSum[blockIdx.x - 1] : 0;
    int off = base + incl[i] - counts[i];
    offsets[i] = off;
    cursor[i] = off;
  }
  if (i == 0) offsets[NN] = EE;
}

__global__ __launch_bounds__(256) void fill(const int* __restrict__ ei,
                                            int* __restrict__ cursor,
                                            int* __restrict__ csr) {
  int e = blockIdx.x * 256 + threadIdx.x;
  if (e < EE) {
    int p = atomicAdd(&cursor[ei[EE + e]], 1);
    csr[p] = ei[e];
  }
}

// ---------------- gather-reduce (bf16 rows): s[n] = feat[n] + sum feat[j] ----
// 16 lanes per node, uint4 (8 bf16) per lane per row; fp32 accumulate/output.
__global__ __launch_bounds__(256) void gather_bf16(const uint4* __restrict__ feat,
                                                   const int* __restrict__ offsets,
                                                   const int* __restrict__ csr,
                                                   float* __restrict__ out) {
  int t = blockIdx.x * 256 + threadIdx.x;
  int g = t >> 4;
  int l = t & 15;
  if (g >= NN) return;
  int beg = offsets[g];
  int end = offsets[g + 1];
  float acc[8] = {};
  acc8(acc, feat[(size_t)g * 16 + l]);           // self term
  int j = beg;
  for (; j + 4 <= end; j += 4) {
    int i0 = csr[j], i1 = csr[j + 1], i2 = csr[j + 2], i3 = csr[j + 3];
    uint4 v0 = feat[(size_t)i0 * 16 + l];
    uint4 v1 = feat[(size_t)i1 * 16 + l];
    uint4 v2 = feat[(size_t)i2 * 16 + l];
    uint4 v3 = feat[(size_t)i3 * 16 + l];
    acc8(acc, v0); acc8(acc, v1); acc8(acc, v2); acc8(acc, v3);
  }
  for (; j < end; ++j) acc8(acc, feat[(size_t)csr[j] * 16 + l]);
  float4* p = (float4*)(out + (size_t)g * FF + l * 8);
  p[0] = make_float4(acc[0], acc[1], acc[2], acc[3]);
  p[1] = make_float4(acc[4], acc[5], acc[6], acc[7]);
}

// ---------------- fp32 GEMM: out = in(nrows x 128) @ w(128x128) + epilogue --------
// OUT16: write bf16 rows (for the next gather); else fp32.
template <bool BN, bool OUT16>
__global__ __launch_bounds__(256) void gemm128(const float* __restrict__ in,
    const float* __restrict__ w, const float* __restrict__ bias,
    const float* __restrict__ gamma, const float* __restrict__ beta,
    const float* __restrict__ rmean, const float* __restrict__ rvar,
    void* __restrict__ out0, int nrows)
{
  __shared__ float in_sT[16][FF];
  __shared__ float w_s[16][FF];
  const int tid = threadIdx.x;
  const int tj = tid & 15;   // col group: cols 8*tj..8*tj+7
  const int tr = tid >> 4;   // row group: rows 8*tr..8*tr+7
  const int row0 = blockIdx.x * 128;
  float acc[8][8] = {};

  const int lr = tid & 127;
  const int lq = tid >> 7;
  const int wr = tid >> 5;
  const int wc = (tid & 31) * 4;
  const int grow = min(row0 + lr, nrows - 1);
  const float* inrow = in + (size_t)grow * FF;

  for (int kc = 0; kc < FF; kc += 16) {
    float4 a0 = *(const float4*)(inrow + kc + 4 * lq);
    float4 a1 = *(const float4*)(inrow + kc + 8 + 4 * lq);
    float4 wv0 = *(const float4*)(w + (size_t)(kc + wr) * FF + wc);
    float4 wv1 = *(const float4*)(w + (size_t)(kc + wr + 8) * FF + wc);
    __syncthreads();
    in_sT[4*lq+0][lr] = a0.x;  in_sT[4*lq+1][lr] = a0.y;
    in_sT[4*lq+2][lr] = a0.z;  in_sT[4*lq+3][lr] = a0.w;
    in_sT[4*lq+8][lr] = a1.x;  in_sT[4*lq+9][lr] = a1.y;
    in_sT[4*lq+10][lr] = a1.z; in_sT[4*lq+11][lr] = a1.w;
    *(float4*)&w_s[wr][wc] = wv0;
    *(float4*)&w_s[wr + 8][wc] = wv1;
    __syncthreads();
#pragma unroll
    for (int k = 0; k < 16; ++k) {
      float4 av0 = *(const float4*)&in_sT[k][8 * tr];
      float4 av1 = *(const float4*)&in_sT[k][8 * tr + 4];
      float4 bv0 = *(const float4*)&w_s[k][8 * tj];
      float4 bv1 = *(const float4*)&w_s[k][8 * tj + 4];
      float a[8] = {av0.x, av0.y, av0.z, av0.w, av1.x, av1.y, av1.z, av1.w};
      float b[8] = {bv0.x, bv0.y, bv0.z, bv0.w, bv1.x, bv1.y, bv1.z, bv1.w};
#pragma unroll
      for (int i = 0; i < 8; ++i)
#pragma unroll
        for (int j = 0; j < 8; ++j)
          acc[i][j] = fmaf(a[i], b[j], acc[i][j]);
    }
  }

  const int c0 = 8 * tj;
  float sc[8], sh[8];
#pragma unroll
  for (int j = 0; j < 8; ++j) {
    if (BN) {
      float s = gamma[c0 + j] * rsqrtf(rvar[c0 + j] + 1e-5f);
      sc[j] = s;
      sh[j] = (bias[c0 + j] - rmean[c0 + j]) * s + beta[c0 + j];
    } else {
      sc[j] = 1.0f;
      sh[j] = bias[c0 + j];
    }
  }
#pragma unroll
  for (int i = 0; i < 8; ++i) {
    int r = row0 + 8 * tr + i;
    if (r < nrows) {
      float o[8];
#pragma unroll
      for (int j = 0; j < 8; ++j) {
        float v = fmaf(acc[i][j], sc[j], sh[j]);
        if (BN) v = fmaxf(v, 0.0f);
        o[j] = v;
      }
      if (OUT16) {
        uint4 pk;
        pk.x = pack2(o[0], o[1]);
        pk.y = pack2(o[2], o[3]);
        pk.z = pack2(o[4], o[5]);
        pk.w = pack2(o[6], o[7]);
        ((uint4*)((ushort*)out0 + (size_t)r * FF))[tj] = pk;
      } else {
        float4* p0 = (float4*)((float*)out0 + (size_t)r * FF + c0);
        p0[0] = make_float4(o[0], o[1], o[2], o[3]);
        p0[1] = make_float4(o[4], o[5], o[6], o[7]);
      }
    }
  }
}

extern "C" void kernel_launch(void* const* d_in, const int* in_sizes, int n_in,
                              void* d_out, int out_size, void* d_ws, size_t ws_size,
                              hipStream_t stream) {
  const float* x     = (const float*)d_in[0];
  const int*   ei    = (const int*)d_in[1];
  const float* w0    = (const float*)d_in[2];
  const float* b0    = (const float*)d_in[3];
  const float* gamma = (const float*)d_in[4];
  const float* beta  = (const float*)d_in[5];
  const float* rmean = (const float*)d_in[6];
  const float* rvar  = (const float*)d_in[7];
  const float* w1    = (const float*)d_in[8];
  const float* b1    = (const float*)d_in[9];
  float* out = (float*)d_out;

  // workspace layout
  float*  s  = (float*)d_ws;                      // NN*FF fp32 (51.2 MB)
  ushort* xb = (ushort*)(s + (size_t)NN * FF);    // NN*FF bf16 (25.6 MB)
  ushort* hb = xb + (size_t)NN * FF;              // NN*FF bf16 (25.6 MB)
  int* counts   = (int*)(hb + (size_t)NN * FF);   // NN
  int* incl     = counts + NN;
  int* chunkSum = incl + NN;                      // 512
  int* offsets  = chunkSum + 512;                 // NN+1
  int* cursor   = offsets + NN + 1;
  int* csr      = cursor + NN;                    // EE

  const int eb = (EE + 255) / 256;
  const int cvb = (NN * FF / 8 + 255) / 256;      // 6250
  const int gatherb = (NN * 16 + 255) / 256;      // 6250
  const int gemmb = (NN + 127) / 128;             // 782

  // ---- CSR build ----
  (void)hipMemsetAsync(counts, 0, (size_t)NN * sizeof(int), stream);
  hist<<<eb, 256, 0, stream>>>(ei, counts);
  scan_chunks<<<NCHUNK, 256, 0, stream>>>(counts, incl, chunkSum);
  scan_sums<<<1, 512, 0, stream>>>(chunkSum);
  finalize<<<NCHUNK, 256, 0, stream>>>(counts, incl, chunkSum, offsets, cursor);
  fill<<<eb, 256, 0, stream>>>(ei, cursor, csr);

  // ---- feature precision convert ----
  cvt_bf16<<<cvb, 256, 0, stream>>>((const float4*)x, (uint4*)xb, NN * FF / 8);

  // ---- layer 1 ----
  gather_bf16<<<gatherb, 256, 0, stream>>>((const uint4*)xb, offsets, csr, s);
  gemm128<true, true><<<gemmb, 256, 0, stream>>>(s, w0, b0, gamma, beta, rmean, rvar,
                                                 (void*)hb, NN);
  // ---- layer 2 ----
  gather_bf16<<<gatherb, 256, 0, stream>>>((const uint4*)hb, offsets, csr, s);
  gemm128<false, false><<<gemmb, 256, 0, stream>>>(s, w1, b1, nullptr, nullptr,
                                                   nullptr, nullptr,
                                                   (void*)out, NN);
}

// Round 6
// 485.144 us; speedup vs baseline: 11.5024x; 1.1083x over previous
//
#include <hip/hip_runtime.h>
#include <cstddef>

#define NN 100000
#define EE 1600000
#define FF 128
#define NCHUNK ((NN + 255) / 256)   // 391

typedef unsigned int uint;
typedef unsigned short ushort;
typedef short short8 __attribute__((ext_vector_type(8)));
typedef float f32x4 __attribute__((ext_vector_type(4)));

__device__ __forceinline__ ushort f2bf(float f) {
  uint u = __float_as_uint(f);
  uint r = u + 0x7fffu + ((u >> 16) & 1u);   // RNE
  return (ushort)(r >> 16);
}
__device__ __forceinline__ uint pack2(float a, float b) {
  return (uint)f2bf(a) | ((uint)f2bf(b) << 16);
}
// accumulate 8 bf16 (one uint4) into 8 fp32
__device__ __forceinline__ void acc8(float* a, uint4 v) {
  a[0] += __uint_as_float(v.x << 16);
  a[1] += __uint_as_float(v.x & 0xffff0000u);
  a[2] += __uint_as_float(v.y << 16);
  a[3] += __uint_as_float(v.y & 0xffff0000u);
  a[4] += __uint_as_float(v.z << 16);
  a[5] += __uint_as_float(v.z & 0xffff0000u);
  a[6] += __uint_as_float(v.w << 16);
  a[7] += __uint_as_float(v.w & 0xffff0000u);
}

// ---------------- x -> bf16 (8 floats / thread) ----------------
__global__ __launch_bounds__(256) void cvt_bf16(const float4* __restrict__ x,
                                                uint4* __restrict__ xb, int n8) {
  int i = blockIdx.x * 256 + threadIdx.x;
  if (i >= n8) return;
  float4 a = x[2 * i];
  float4 b = x[2 * i + 1];
  uint4 o;
  o.x = pack2(a.x, a.y);
  o.y = pack2(a.z, a.w);
  o.z = pack2(b.x, b.y);
  o.w = pack2(b.z, b.w);
  xb[i] = o;
}

// ---------------- w (fp32 [k][n]) -> wt (bf16 [n][k]) ----------------
__global__ __launch_bounds__(256) void cvt_wt(const float* __restrict__ w,
                                              ushort* __restrict__ wt) {
  int i = blockIdx.x * 256 + threadIdx.x;   // 0..16383
  int k = i >> 7, n = i & 127;
  wt[n * FF + k] = f2bf(w[(size_t)k * FF + n]);
}

// ---------------- CSR build ----------------
__global__ __launch_bounds__(256) void hist(const int* __restrict__ ei,
                                            int* __restrict__ counts) {
  int e = blockIdx.x * 256 + threadIdx.x;
  if (e < EE) atomicAdd(&counts[ei[EE + e]], 1);
}

__global__ __launch_bounds__(256) void scan_chunks(const int* __restrict__ counts,
                                                   int* __restrict__ incl,
                                                   int* __restrict__ chunkSum) {
  __shared__ int sd[256];
  int i = blockIdx.x * 256 + threadIdx.x;
  sd[threadIdx.x] = (i < NN) ? counts[i] : 0;
  __syncthreads();
  for (int off = 1; off < 256; off <<= 1) {
    int t = 0;
    if ((int)threadIdx.x >= off) t = sd[threadIdx.x - off];
    __syncthreads();
    if ((int)threadIdx.x >= off) sd[threadIdx.x] += t;
    __syncthreads();
  }
  if (i < NN) incl[i] = sd[threadIdx.x];
  if (threadIdx.x == 255) chunkSum[blockIdx.x] = sd[255];
}

__global__ __launch_bounds__(512) void scan_sums(int* __restrict__ chunkSum) {
  __shared__ int sd[512];
  sd[threadIdx.x] = (threadIdx.x < NCHUNK) ? chunkSum[threadIdx.x] : 0;
  __syncthreads();
  for (int off = 1; off < 512; off <<= 1) {
    int t = 0;
    if ((int)threadIdx.x >= off) t = sd[threadIdx.x - off];
    __syncthreads();
    if ((int)threadIdx.x >= off) sd[threadIdx.x] += t;
    __syncthreads();
  }
  if (threadIdx.x < NCHUNK) chunkSum[threadIdx.x] = sd[threadIdx.x];
}

__global__ __launch_bounds__(256) void finalize(const int* __restrict__ counts,
                                                const int* __restrict__ incl,
                                                const int* __restrict__ chunkSum,
                                                int* __restrict__ offsets,
                                                int* __restrict__ cursor) {
  int i = blockIdx.x * 256 + threadIdx.x;
  if (i < NN) {
    int base = (blockIdx.x > 0) ? chunkSum[blockIdx.x - 1] : 0;
    int off = base + incl[i] - counts[i];
    offsets[i] = off;
    cursor[i] = off;
  }
  if (i == 0) offsets[NN] = EE;
}

__global__ __launch_bounds__(256) void fill(const int* __restrict__ ei,
                                            int* __restrict__ cursor,
                                            int* __restrict__ csr) {
  int e = blockIdx.x * 256 + threadIdx.x;
  if (e < EE) {
    int p = atomicAdd(&cursor[ei[EE + e]], 1);
    csr[p] = ei[e];
  }
}

// ---------------- gather-reduce (bf16 rows -> bf16 rows) ----------------
// s[n] = feat[n] + sum_{j in N(n)} feat[j]; fp32 accumulate, bf16 out.
__global__ __launch_bounds__(256) void gather_bf16(const uint4* __restrict__ feat,
                                                   const int* __restrict__ offsets,
                                                   const int* __restrict__ csr,
                                                   ushort* __restrict__ out) {
  int t = blockIdx.x * 256 + threadIdx.x;
  int g = t >> 4;
  int l = t & 15;
  if (g >= NN) return;
  int beg = offsets[g];
  int end = offsets[g + 1];
  float acc[8] = {};
  acc8(acc, feat[(size_t)g * 16 + l]);           // self term
  int j = beg;
  for (; j + 4 <= end; j += 4) {
    int i0 = csr[j], i1 = csr[j + 1], i2 = csr[j + 2], i3 = csr[j + 3];
    uint4 v0 = feat[(size_t)i0 * 16 + l];
    uint4 v1 = feat[(size_t)i1 * 16 + l];
    uint4 v2 = feat[(size_t)i2 * 16 + l];
    uint4 v3 = feat[(size_t)i3 * 16 + l];
    acc8(acc, v0); acc8(acc, v1); acc8(acc, v2); acc8(acc, v3);
  }
  for (; j < end; ++j) acc8(acc, feat[(size_t)csr[j] * 16 + l]);
  uint4 o;
  o.x = pack2(acc[0], acc[1]);
  o.y = pack2(acc[2], acc[3]);
  o.z = pack2(acc[4], acc[5]);
  o.w = pack2(acc[6], acc[7]);
  ((uint4*)(out + (size_t)g * FF))[l] = o;
}

// ---------------- bf16 MFMA GEMM: out = a(nrows x 128) @ w(128x128) + epilogue ----
// a: bf16 row-major; bt: bf16 [n][k] (transposed weights, L1-resident 32 KB).
// No LDS: A-frags are coalesced read-once global loads; B-frags hit L1.
// Wave w of 4 handles rows [blk*128 + w*32, +32); acc = 16 f32x4 tiles.
template <bool BN, bool OUT16>
__global__ __launch_bounds__(256) void gemm_mfma(const ushort* __restrict__ a,
    const ushort* __restrict__ bt, const float* __restrict__ bias,
    const float* __restrict__ gamma, const float* __restrict__ beta,
    const float* __restrict__ rmean, const float* __restrict__ rvar,
    void* __restrict__ out0, int nrows)
{
  const int tid = threadIdx.x;
  const int wv = tid >> 6;
  const int l = tid & 63;
  const int lane16 = l & 15;
  const int quad = l >> 4;
  const int rowbase = blockIdx.x * 128 + wv * 32;

  f32x4 acc[2][8] = {};

  for (int kc = 0; kc < FF; kc += 32) {
    short8 af[2];
#pragma unroll
    for (int rt = 0; rt < 2; ++rt) {
      int r = min(rowbase + rt * 16 + lane16, nrows - 1);
      af[rt] = *(const short8*)(a + (size_t)r * FF + kc + quad * 8);
    }
#pragma unroll
    for (int ct = 0; ct < 8; ++ct) {
      int n = ct * 16 + lane16;
      short8 bf = *(const short8*)(bt + n * FF + kc + quad * 8);
      acc[0][ct] = __builtin_amdgcn_mfma_f32_16x16x32_bf16(af[0], bf, acc[0][ct], 0, 0, 0);
      acc[1][ct] = __builtin_amdgcn_mfma_f32_16x16x32_bf16(af[1], bf, acc[1][ct], 0, 0, 0);
    }
  }

  // per-col scale/shift (col = ct*16 + lane16)
  float sc[8], sh[8];
#pragma unroll
  for (int ct = 0; ct < 8; ++ct) {
    int c = ct * 16 + lane16;
    if (BN) {
      float s = gamma[c] * rsqrtf(rvar[c] + 1e-5f);
      sc[ct] = s;
      sh[ct] = (bias[c] - rmean[c]) * s + beta[c];
    } else {
      sc[ct] = 1.0f;
      sh[ct] = bias[c];
    }
  }

#pragma unroll
  for (int rt = 0; rt < 2; ++rt) {
#pragma unroll
    for (int reg = 0; reg < 4; ++reg) {
      int r = rowbase + rt * 16 + quad * 4 + reg;
      if (r < nrows) {
#pragma unroll
        for (int ct = 0; ct < 8; ++ct) {
          int c = ct * 16 + lane16;
          float v = fmaf(acc[rt][ct][reg], sc[ct], sh[ct]);
          if (BN) v = fmaxf(v, 0.0f);
          if (OUT16) ((ushort*)out0)[(size_t)r * FF + c] = f2bf(v);
          else       ((float*)out0)[(size_t)r * FF + c] = v;
        }
      }
    }
  }
}

extern "C" void kernel_launch(void* const* d_in, const int* in_sizes, int n_in,
                              void* d_out, int out_size, void* d_ws, size_t ws_size,
                              hipStream_t stream) {
  const float* x     = (const float*)d_in[0];
  const int*   ei    = (const int*)d_in[1];
  const float* w0    = (const float*)d_in[2];
  const float* b0    = (const float*)d_in[3];
  const float* gamma = (const float*)d_in[4];
  const float* beta  = (const float*)d_in[5];
  const float* rmean = (const float*)d_in[6];
  const float* rvar  = (const float*)d_in[7];
  const float* w1    = (const float*)d_in[8];
  const float* b1    = (const float*)d_in[9];
  float* out = (float*)d_out;

  // workspace layout (all bf16 feature buffers)
  ushort* sb  = (ushort*)d_ws;                    // NN*FF
  ushort* xb  = sb + (size_t)NN * FF;             // NN*FF
  ushort* hb  = xb + (size_t)NN * FF;             // NN*FF
  ushort* wt0 = hb + (size_t)NN * FF;             // 128*128
  ushort* wt1 = wt0 + FF * FF;                    // 128*128
  int* counts   = (int*)(wt1 + FF * FF);          // NN
  int* incl     = counts + NN;
  int* chunkSum = incl + NN;                      // 512
  int* offsets  = chunkSum + 512;                 // NN+1
  int* cursor   = offsets + NN + 1;
  int* csr      = cursor + NN;                    // EE

  const int eb = (EE + 255) / 256;
  const int cvb = (NN * FF / 8 + 255) / 256;      // 6250
  const int gatherb = (NN * 16 + 255) / 256;      // 6250
  const int gemmb = (NN + 127) / 128;             // 782

  // ---- CSR build ----
  (void)hipMemsetAsync(counts, 0, (size_t)NN * sizeof(int), stream);
  hist<<<eb, 256, 0, stream>>>(ei, counts);
  scan_chunks<<<NCHUNK, 256, 0, stream>>>(counts, incl, chunkSum);
  scan_sums<<<1, 512, 0, stream>>>(chunkSum);
  finalize<<<NCHUNK, 256, 0, stream>>>(counts, incl, chunkSum, offsets, cursor);
  fill<<<eb, 256, 0, stream>>>(ei, cursor, csr);

  // ---- precision converts ----
  cvt_bf16<<<cvb, 256, 0, stream>>>((const float4*)x, (uint4*)xb, NN * FF / 8);
  cvt_wt<<<64, 256, 0, stream>>>(w0, wt0);
  cvt_wt<<<64, 256, 0, stream>>>(w1, wt1);

  // ---- layer 1 ----
  gather_bf16<<<gatherb, 256, 0, stream>>>((const uint4*)xb, offsets, csr, sb);
  gemm_mfma<true, true><<<gemmb, 256, 0, stream>>>(sb, wt0, b0, gamma, beta,
                                                   rmean, rvar, (void*)hb, NN);
  // ---- layer 2 ----
  gather_bf16<<<gatherb, 256, 0, stream>>>((const uint4*)hb, offsets, csr, sb);
  gemm_mfma<false, false><<<gemmb, 256, 0, stream>>>(sb, wt1, b1, nullptr, nullptr,
                                                     nullptr, nullptr, (void*)out, NN);
}

// Round 7
// 415.229 us; speedup vs baseline: 13.4391x; 1.1684x over previous
//
#include <hip/hip_runtime.h>
#include <cstddef>

#define NN 100000
#define EE 1600000
#define FF 128
#define NCHUNK ((NN + 255) / 256)   // 391
#define BSH 9                        // 512 nodes per bucket
#define NB ((NN + 511) / 512)        // 196 buckets
#define EPB 4096                     // edges per binscatter block

typedef unsigned int uint;
typedef unsigned short ushort;
typedef short short8 __attribute__((ext_vector_type(8)));
typedef float f32x4 __attribute__((ext_vector_type(4)));

__device__ __forceinline__ ushort f2bf(float f) {
  uint u = __float_as_uint(f);
  uint r = u + 0x7fffu + ((u >> 16) & 1u);   // RNE
  return (ushort)(r >> 16);
}
__device__ __forceinline__ uint pack2(float a, float b) {
  return (uint)f2bf(a) | ((uint)f2bf(b) << 16);
}
// accumulate 8 bf16 (one uint4) into 8 fp32
__device__ __forceinline__ void acc8(float* a, uint4 v) {
  a[0] += __uint_as_float(v.x << 16);
  a[1] += __uint_as_float(v.x & 0xffff0000u);
  a[2] += __uint_as_float(v.y << 16);
  a[3] += __uint_as_float(v.y & 0xffff0000u);
  a[4] += __uint_as_float(v.z << 16);
  a[5] += __uint_as_float(v.z & 0xffff0000u);
  a[6] += __uint_as_float(v.w << 16);
  a[7] += __uint_as_float(v.w & 0xffff0000u);
}

// ---------------- x -> bf16 (8 floats / thread) ----------------
__global__ __launch_bounds__(256) void cvt_bf16(const float4* __restrict__ x,
                                                uint4* __restrict__ xb, int n8) {
  int i = blockIdx.x * 256 + threadIdx.x;
  if (i >= n8) return;
  float4 a = x[2 * i];
  float4 b = x[2 * i + 1];
  uint4 o;
  o.x = pack2(a.x, a.y);
  o.y = pack2(a.z, a.w);
  o.z = pack2(b.x, b.y);
  o.w = pack2(b.z, b.w);
  xb[i] = o;
}

// ---------------- w (fp32 [k][n]) -> wt (bf16 [n][k]) ----------------
__global__ __launch_bounds__(256) void cvt_wt(const float* __restrict__ w,
                                              ushort* __restrict__ wt) {
  int i = blockIdx.x * 256 + threadIdx.x;   // 0..16383
  int k = i >> 7, n = i & 127;
  wt[n * FF + k] = f2bf(w[(size_t)k * FF + n]);
}

// ---------------- CSR build ----------------
__global__ __launch_bounds__(256) void hist(const int* __restrict__ ei,
                                            int* __restrict__ counts) {
  int e = blockIdx.x * 256 + threadIdx.x;
  if (e < EE) atomicAdd(&counts[ei[EE + e]], 1);
}

__global__ __launch_bounds__(256) void scan_chunks(const int* __restrict__ counts,
                                                   int* __restrict__ incl,
                                                   int* __restrict__ chunkSum) {
  __shared__ int sd[256];
  int i = blockIdx.x * 256 + threadIdx.x;
  sd[threadIdx.x] = (i < NN) ? counts[i] : 0;
  __syncthreads();
  for (int off = 1; off < 256; off <<= 1) {
    int t = 0;
    if ((int)threadIdx.x >= off) t = sd[threadIdx.x - off];
    __syncthreads();
    if ((int)threadIdx.x >= off) sd[threadIdx.x] += t;
    __syncthreads();
  }
  if (i < NN) incl[i] = sd[threadIdx.x];
  if (threadIdx.x == 255) chunkSum[blockIdx.x] = sd[255];
}

__global__ __launch_bounds__(512) void scan_sums(int* __restrict__ chunkSum) {
  __shared__ int sd[512];
  sd[threadIdx.x] = (threadIdx.x < NCHUNK) ? chunkSum[threadIdx.x] : 0;
  __syncthreads();
  for (int off = 1; off < 512; off <<= 1) {
    int t = 0;
    if ((int)threadIdx.x >= off) t = sd[threadIdx.x - off];
    __syncthreads();
    if ((int)threadIdx.x >= off) sd[threadIdx.x] += t;
    __syncthreads();
  }
  if (threadIdx.x < NCHUNK) chunkSum[threadIdx.x] = sd[threadIdx.x];
}

__global__ __launch_bounds__(256) void finalize(const int* __restrict__ counts,
                                                const int* __restrict__ incl,
                                                const int* __restrict__ chunkSum,
                                                int* __restrict__ offsets) {
  int i = blockIdx.x * 256 + threadIdx.x;
  if (i < NN) {
    int base = (blockIdx.x > 0) ? chunkSum[blockIdx.x - 1] : 0;
    offsets[i] = base + incl[i] - counts[i];
  }
  if (i == 0) offsets[NN] = EE;
}

// bucket cursors: bcur[b] = offsets[b*512] (chunk boundary -> from chunkSum)
__global__ __launch_bounds__(256) void init_bcur(const int* __restrict__ chunkSum,
                                                 int* __restrict__ bcur) {
  int b = blockIdx.x * 256 + threadIdx.x;
  if (b < NB) bcur[b] = b ? chunkSum[2 * b - 1] : 0;
}

// ---- binscatter: LDS counting-sort 4096 edges by bucket, coalesced dump ----
__global__ __launch_bounds__(256) void binscatter(const int* __restrict__ ei,
                                                  int* __restrict__ bcur,
                                                  uint2* __restrict__ pairs) {
  __shared__ uint2 lpair[EPB];     // 32 KB
  __shared__ int hcnt[256];        // hist, then local scatter cursor
  __shared__ int hincl[256];       // inclusive scan over buckets
  __shared__ int hbase[256];       // global base per bucket
  const int t = threadIdx.x;
  const int e0 = blockIdx.x * EPB;

  hcnt[t] = 0;
  __syncthreads();

  int es[16], ed[16];
#pragma unroll
  for (int i = 0; i < 16; ++i) {
    int e = e0 + t + i * 256;
    if (e < EE) {
      es[i] = ei[e];
      ed[i] = ei[EE + e];
      atomicAdd(&hcnt[ed[i] >> BSH], 1);
    } else {
      es[i] = -1;
      ed[i] = 0;
    }
  }
  __syncthreads();

  const int mycnt = hcnt[t];
  hincl[t] = mycnt;
  __syncthreads();
  for (int off = 1; off < 256; off <<= 1) {
    int tv = 0;
    if (t >= off) tv = hincl[t - off];
    __syncthreads();
    if (t >= off) hincl[t] += tv;
    __syncthreads();
  }
  // reserve global range (one atomic per non-empty bucket per block)
  if (t < NB && mycnt > 0) hbase[t] = atomicAdd(&bcur[t], mycnt);
  const int lbase = hincl[t] - mycnt;
  __syncthreads();
  hcnt[t] = lbase;                 // becomes local scatter cursor
  __syncthreads();

#pragma unroll
  for (int i = 0; i < 16; ++i) {
    if (es[i] >= 0) {
      int b = ed[i] >> BSH;
      int pos = atomicAdd(&hcnt[b], 1);
      lpair[pos] = make_uint2((uint)es[i], (uint)ed[i]);
    }
  }
  __syncthreads();

  const int total = hincl[255];
  for (int i = t; i < total; i += 256) {
    // smallest b with hincl[b] > i
    int lo = 0, hi = 255;
    while (lo < hi) {
      int mid = (lo + hi) >> 1;
      if (hincl[mid] > i) hi = mid; else lo = mid + 1;
    }
    int b = lo;
    int lb = b ? hincl[b - 1] : 0;
    pairs[(size_t)hbase[b] + (i - lb)] = lpair[i];
  }
}

// ---- fill2: one block per bucket; per-node cursors in LDS; L2-local writes ----
__global__ __launch_bounds__(256) void fill2(const uint2* __restrict__ pairs,
                                             const int* __restrict__ offsets,
                                             int* __restrict__ csr) {
  __shared__ int cur[512];
  const int t = threadIdx.x;
  const int v0 = blockIdx.x << BSH;
  const int v1 = min(v0 + 512, NN);
  for (int i = t; i < 512; i += 256) {
    int v = v0 + i;
    cur[i] = (v < NN) ? offsets[v] : 0;
  }
  __syncthreads();
  const int pbeg = offsets[v0];
  const int pend = offsets[v1];
  for (int j = pbeg + t; j < pend; j += 256) {
    uint2 p = pairs[j];
    int pos = atomicAdd(&cur[(int)p.y - v0], 1);
    csr[pos] = (int)p.x;
  }
}

// ---------------- gather-reduce (bf16 rows -> bf16 rows) ----------------
__global__ __launch_bounds__(256) void gather_bf16(const uint4* __restrict__ feat,
                                                   const int* __restrict__ offsets,
                                                   const int* __restrict__ csr,
                                                   ushort* __restrict__ out) {
  int t = blockIdx.x * 256 + threadIdx.x;
  int g = t >> 4;
  int l = t & 15;
  if (g >= NN) return;
  int beg = offsets[g];
  int end = offsets[g + 1];
  float acc[8] = {};
  acc8(acc, feat[(size_t)g * 16 + l]);           // self term
  int j = beg;
  for (; j + 4 <= end; j += 4) {
    int i0 = csr[j], i1 = csr[j + 1], i2 = csr[j + 2], i3 = csr[j + 3];
    uint4 v0 = feat[(size_t)i0 * 16 + l];
    uint4 v1 = feat[(size_t)i1 * 16 + l];
    uint4 v2 = feat[(size_t)i2 * 16 + l];
    uint4 v3 = feat[(size_t)i3 * 16 + l];
    acc8(acc, v0); acc8(acc, v1); acc8(acc, v2); acc8(acc, v3);
  }
  for (; j < end; ++j) acc8(acc, feat[(size_t)csr[j] * 16 + l]);
  uint4 o;
  o.x = pack2(acc[0], acc[1]);
  o.y = pack2(acc[2], acc[3]);
  o.z = pack2(acc[4], acc[5]);
  o.w = pack2(acc[6], acc[7]);
  ((uint4*)(out + (size_t)g * FF))[l] = o;
}

// ---------------- bf16 MFMA GEMM (no LDS) ----------------
template <bool BN, bool OUT16>
__global__ __launch_bounds__(256) void gemm_mfma(const ushort* __restrict__ a,
    const ushort* __restrict__ bt, const float* __restrict__ bias,
    const float* __restrict__ gamma, const float* __restrict__ beta,
    const float* __restrict__ rmean, const float* __restrict__ rvar,
    void* __restrict__ out0, int nrows)
{
  const int tid = threadIdx.x;
  const int wv = tid >> 6;
  const int l = tid & 63;
  const int lane16 = l & 15;
  const int quad = l >> 4;
  const int rowbase = blockIdx.x * 128 + wv * 32;

  f32x4 acc[2][8] = {};

  for (int kc = 0; kc < FF; kc += 32) {
    short8 af[2];
#pragma unroll
    for (int rt = 0; rt < 2; ++rt) {
      int r = min(rowbase + rt * 16 + lane16, nrows - 1);
      af[rt] = *(const short8*)(a + (size_t)r * FF + kc + quad * 8);
    }
#pragma unroll
    for (int ct = 0; ct < 8; ++ct) {
      int n = ct * 16 + lane16;
      short8 bf = *(const short8*)(bt + n * FF + kc + quad * 8);
      acc[0][ct] = __builtin_amdgcn_mfma_f32_16x16x32_bf16(af[0], bf, acc[0][ct], 0, 0, 0);
      acc[1][ct] = __builtin_amdgcn_mfma_f32_16x16x32_bf16(af[1], bf, acc[1][ct], 0, 0, 0);
    }
  }

  float sc[8], sh[8];
#pragma unroll
  for (int ct = 0; ct < 8; ++ct) {
    int c = ct * 16 + lane16;
    if (BN) {
      float s = gamma[c] * rsqrtf(rvar[c] + 1e-5f);
      sc[ct] = s;
      sh[ct] = (bias[c] - rmean[c]) * s + beta[c];
    } else {
      sc[ct] = 1.0f;
      sh[ct] = bias[c];
    }
  }

#pragma unroll
  for (int rt = 0; rt < 2; ++rt) {
#pragma unroll
    for (int reg = 0; reg < 4; ++reg) {
      int r = rowbase + rt * 16 + quad * 4 + reg;
      if (r < nrows) {
#pragma unroll
        for (int ct = 0; ct < 8; ++ct) {
          int c = ct * 16 + lane16;
          float v = fmaf(acc[rt][ct][reg], sc[ct], sh[ct]);
          if (BN) v = fmaxf(v, 0.0f);
          if (OUT16) ((ushort*)out0)[(size_t)r * FF + c] = f2bf(v);
          else       ((float*)out0)[(size_t)r * FF + c] = v;
        }
      }
    }
  }
}

extern "C" void kernel_launch(void* const* d_in, const int* in_sizes, int n_in,
                              void* d_out, int out_size, void* d_ws, size_t ws_size,
                              hipStream_t stream) {
  const float* x     = (const float*)d_in[0];
  const int*   ei    = (const int*)d_in[1];
  const float* w0    = (const float*)d_in[2];
  const float* b0    = (const float*)d_in[3];
  const float* gamma = (const float*)d_in[4];
  const float* beta  = (const float*)d_in[5];
  const float* rmean = (const float*)d_in[6];
  const float* rvar  = (const float*)d_in[7];
  const float* w1    = (const float*)d_in[8];
  const float* b1    = (const float*)d_in[9];
  float* out = (float*)d_out;

  // workspace layout (pairs placed 8B-aligned right after bf16 buffers)
  ushort* sb  = (ushort*)d_ws;                    // NN*FF
  ushort* xb  = sb + (size_t)NN * FF;             // NN*FF
  ushort* hb  = xb + (size_t)NN * FF;             // NN*FF
  ushort* wt0 = hb + (size_t)NN * FF;             // 128*128
  ushort* wt1 = wt0 + FF * FF;                    // 128*128
  uint2* pairs  = (uint2*)(wt1 + FF * FF);        // EE uint2 (12.8 MB)
  int* csr      = (int*)(pairs + (size_t)EE);     // EE
  int* counts   = csr + EE;                       // NN
  int* incl     = counts + NN;                    // NN
  int* chunkSum = incl + NN;                      // 512
  int* offsets  = chunkSum + 512;                 // NN+1
  int* bcur     = offsets + NN + 1;               // NB (+pad)

  const int eb = (EE + 255) / 256;
  const int cvb = (NN * FF / 8 + 255) / 256;      // 6250
  const int gatherb = (NN * 16 + 255) / 256;      // 6250
  const int gemmb = (NN + 127) / 128;             // 782
  const int binb = (EE + EPB - 1) / EPB;          // 391

  // ---- CSR build ----
  (void)hipMemsetAsync(counts, 0, (size_t)NN * sizeof(int), stream);
  hist<<<eb, 256, 0, stream>>>(ei, counts);
  scan_chunks<<<NCHUNK, 256, 0, stream>>>(counts, incl, chunkSum);
  scan_sums<<<1, 512, 0, stream>>>(chunkSum);
  finalize<<<NCHUNK, 256, 0, stream>>>(counts, incl, chunkSum, offsets);
  init_bcur<<<1, 256, 0, stream>>>(chunkSum, bcur);
  binscatter<<<binb, 256, 0, stream>>>(ei, bcur, pairs);
  fill2<<<NB, 256, 0, stream>>>(pairs, offsets, csr);

  // ---- precision converts ----
  cvt_bf16<<<cvb, 256, 0, stream>>>((const float4*)x, (uint4*)xb, NN * FF / 8);
  cvt_wt<<<64, 256, 0, stream>>>(w0, wt0);
  cvt_wt<<<64, 256, 0, stream>>>(w1, wt1);

  // ---- layer 1 ----
  gather_bf16<<<gatherb, 256, 0, stream>>>((const uint4*)xb, offsets, csr, sb);
  gemm_mfma<true, true><<<gemmb, 256, 0, stream>>>(sb, wt0, b0, gamma, beta,
                                                   rmean, rvar, (void*)hb, NN);
  // ---- layer 2 ----
  gather_bf16<<<gatherb, 256, 0, stream>>>((const uint4*)hb, offsets, csr, sb);
  gemm_mfma<false, false><<<gemmb, 256, 0, stream>>>(sb, wt1, b1, nullptr, nullptr,
                                                     nullptr, nullptr, (void*)out, NN);
}